// Round 18
// baseline (228.074 us; speedup 1.0000x reference)
//
#include <hip/hip_runtime.h>
#include <math.h>

typedef unsigned long long u64;
typedef _Float16 f16x8 __attribute__((ext_vector_type(8)));
typedef float f32x16 __attribute__((ext_vector_type(16)));

#define N_PTS 12000
#define KNN 16
#define QB 16                            // queries per block (M rows 0..15 real, 16..31 zero-pad)
#define NWAVES 8                         // waves per block (512 threads)
#define NGROUPS32 (N_PTS / 32)           // 375 candidate groups of 32
#define TAU_PTS 2048
#define TAU_GROUPS32 (TAU_PTS / 32)      // 64
#define CAP 384                          // survivor capacity; 6 offers/lane
#define MARGIN 0.08f                     // > 2*m, m = f16 d2 error bound ~0.032

// ---------------------------------------------------------------------------
// Kernel 1: encoders. feats = tanh(x@Wf+bf); coords = tanh(x@Wl+bl) fp32+f16;
// sq = |coords|^2. One wave per row.
// ---------------------------------------------------------------------------
__global__ __launch_bounds__(256) void encoder_kernel(
    const float* __restrict__ x, const float* __restrict__ Wf, const float* __restrict__ bf,
    const float* __restrict__ Wl, const float* __restrict__ bl,
    float* __restrict__ feats, float* __restrict__ coords, _Float16* __restrict__ coords_h,
    float* __restrict__ sq)
{
  const int wave = threadIdx.x >> 6;
  const int lane = threadIdx.x & 63;
  const int i = blockIdx.x * 4 + wave;
  if (i >= N_PTS) return;
  float xv = x[i * 64 + lane];
  float accf = bf[lane];
  float accc = bl[lane & 15];
  #pragma unroll
  for (int k = 0; k < 64; ++k) {
    float xk = __shfl(xv, k);
    accf = fmaf(xk, Wf[k * 64 + lane], accf);
    accc = fmaf(xk, Wl[k * 16 + (lane & 15)], accc);
  }
  feats[i * 64 + lane] = tanhf(accf);
  float c = tanhf(accc);
  float cc = (lane < 16) ? c * c : 0.0f;
  cc += __shfl_xor(cc, 1);
  cc += __shfl_xor(cc, 2);
  cc += __shfl_xor(cc, 4);
  cc += __shfl_xor(cc, 8);
  if (lane < 16) {
    coords[i * 16 + lane] = c;
    coords_h[i * 16 + lane] = (_Float16)c;
  }
  if (lane == 0) sq[i] = cc;
}

// ---------------------------------------------------------------------------
// u64-key helpers. Keys (f32bits(d2)<<32)|j unique; sentinels (0x7F00000t<<32)
// exceed any real key; ~0ull matches no slot.
// ---------------------------------------------------------------------------
__device__ __forceinline__ void ins6(u64 key, u64* k6, u64& kmax) {
  const u64 om = (key < kmax) ? kmax : ~0ull;
  #pragma unroll
  for (int t = 0; t < 6; ++t)
    k6[t] = (k6[t] == om) ? key : k6[t];
  u64 a = k6[0] > k6[1] ? k6[0] : k6[1];
  u64 b = k6[2] > k6[3] ? k6[2] : k6[3];
  u64 c = k6[4] > k6[5] ? k6[4] : k6[5];
  a = a > b ? a : b;
  kmax = a > c ? a : c;
}

__device__ __forceinline__ u64 shflx_u64(u64 v, int off) {
  int lo = __shfl_xor((int)(unsigned)v, off);
  int hi = __shfl_xor((int)(unsigned)(v >> 32), off);
  return ((u64)(unsigned)hi << 32) | (unsigned)lo;
}

__device__ __forceinline__ u64 minbfly(u64 m) {
  #pragma unroll
  for (int off = 32; off >= 1; off >>= 1) {
    u64 o = shflx_u64(m, off);
    m = (o < m) ? o : m;
  }
  return m;
}

// ---------------------------------------------------------------------------
// Kernel 2: 32x32x16-MFMA KNN + gaussian aggregation + fused output GEMM +
// INLINE exact overflow fallback (no separate fixup dispatch; overflow is
// block-local so the owning wave handles it in place, P~1e-4/run).
// Block = 16 queries (A rows 0..15 real, 16..31 zero), 8 waves. Per 32-cand
// group: one full-wave coalesced B load + one mfma_f32_32x32x16_f16 (K=16
// exact). C layout (m74/m101-verified): col=lane&31,
// row=(r&3)+8*(r>>2)+4*(lane>>5).
// Phase A: per-lane minima -> 64 disjoint 32-pt-subset cell minima via LDS
//   atomicMin on clamped f32 bits; tau = 16th order stat (bitonic) + MARGIN.
//   SOUND: 16 smallest cells are 16 distinct points => bound >= true 16th.
// Phase B: full scan, gate, push u16 index. Phase C: exact fp32 re-score +
//   6-slot tables + minbfly (<=6 offers/lane: no eviction -> exact).
// Epilogue: block GEMM out = concat(feats,agg)@Wo + bo.
// ---------------------------------------------------------------------------
__global__ __launch_bounds__(512) void knn_agg_kernel(
    const float* __restrict__ coords, const _Float16* __restrict__ coords_h,
    const float* __restrict__ sq, const float* __restrict__ feats,
    const float* __restrict__ Wo, const float* __restrict__ bo,
    float* __restrict__ out)
{
  __shared__ unsigned short sbuf[QB][CAP];   // 12288 B
  __shared__ int scnt[QB];                   //    64 B
  __shared__ unsigned colminS[QB][64];       //  4096 B
  __shared__ float taugS[QB];                //    64 B
  __shared__ float featS[QB][64];            //  4096 B
  __shared__ float aggS[QB][64];             //  4096 B

  const int tid = threadIdx.x;       // 0..511
  const int lane = tid & 63;
  const int wave = tid >> 6;         // 0..7
  const int qbase = blockIdx.x * QB;
  const int mcol = lane & 31;        // A row / B col
  const int half = lane >> 5;        // k-half (0: k=0..7, 1: k=8..15)

  if (tid < QB) scnt[tid] = 0;
  #pragma unroll
  for (int t = tid; t < QB * 64; t += 512)
    ((unsigned*)colminS)[t] = 0x7F800000u;   // +INF bits

  // A fragment: A[m=lane&31][k=half*8+j]; rows >=16 zero (padding)
  f16x8 afrag = {0, 0, 0, 0, 0, 0, 0, 0};
  if (mcol < QB) {
    const uint4 u = *(const uint4*)((const char*)coords_h + (qbase + mcol) * 32 + half * 16);
    afrag = __builtin_bit_cast(f16x8, u);
  }
  // rows handled by this lane: row(r) = (r>>2)*8 + 4*half + (r&3), r=0..7
  float sqi8[8];
  #pragma unroll
  for (int blk = 0; blk < 2; ++blk) {
    const float4 v = *(const float4*)&sq[qbase + blk * 8 + 4 * half];
    sqi8[blk * 4 + 0] = v.x; sqi8[blk * 4 + 1] = v.y;
    sqi8[blk * 4 + 2] = v.z; sqi8[blk * 4 + 3] = v.w;
  }
  __syncthreads();   // scnt + colminS init visible

  // ===================== Phase A: sample scan -> cell minima =================
  float lmin8[8] = {INFINITY, INFINITY, INFINITY, INFINITY,
                    INFINITY, INFINITY, INFINITY, INFINITY};
  for (int g = wave; g < TAU_GROUPS32; g += NWAVES) {
    const int j0 = g * 32;
    const uint4 u = *(const uint4*)((const char*)coords_h + (j0 + mcol) * 32 + half * 16);
    const f16x8 bfrag = __builtin_bit_cast(f16x8, u);
    const float sqj = sq[j0 + mcol];
    f32x16 acc = {0.0f};
    acc = __builtin_amdgcn_mfma_f32_32x32x16_f16(afrag, bfrag, acc, 0, 0, 0);
    #pragma unroll
    for (int r = 0; r < 8; ++r) {
      const int row = (r >> 2) * 8 + 4 * half + (r & 3);
      float d2a = fmaf(-2.0f, acc[r], sqi8[r] + sqj);
      if (j0 + mcol == qbase + row) d2a = INFINITY;  // exclude self
      lmin8[r] = fminf(lmin8[r], d2a);
    }
  }
  {
    const int cell = mcol * 2 + (wave >> 2);  // 64 disjoint 32-pt subsets
    #pragma unroll
    for (int r = 0; r < 8; ++r) {
      const int row = (r >> 2) * 8 + 4 * half + (r & 3);
      atomicMin(&colminS[row][cell], __float_as_uint(fmaxf(lmin8[r], 0.0f)));
    }
  }
  __syncthreads();

  // tau per query: 16th order stat of the 64 cell minima (bitonic, lane 15)
  #pragma unroll
  for (int s = 0; s < 2; ++s) {
    const int q = wave * 2 + s;
    float v = __uint_as_float(colminS[q][lane]);
    #pragma unroll
    for (int k = 2; k <= 64; k <<= 1) {
      #pragma unroll
      for (int st = k >> 1; st >= 1; st >>= 1) {
        const float o = __shfl_xor(v, st);
        const bool keepMin = (((lane & st) == 0) == ((lane & k) == 0));
        const float mn = fminf(v, o), mx = fmaxf(v, o);
        v = keepMin ? mn : mx;
      }
    }
    const float tq = __shfl(v, 15) + MARGIN;   // sound gate
    if (lane == 0) taugS[q] = tq;
  }
  __syncthreads();

  float taug8[8];
  #pragma unroll
  for (int r = 0; r < 8; ++r)
    taug8[r] = taugS[(r >> 2) * 8 + 4 * half + (r & 3)];

  // ===================== Phase B: full MFMA scan, push survivors ============
  for (int g = wave; g < NGROUPS32; g += NWAVES) {
    const int j0 = g * 32;
    const uint4 u = *(const uint4*)((const char*)coords_h + (j0 + mcol) * 32 + half * 16);
    const f16x8 bfrag = __builtin_bit_cast(f16x8, u);
    const float sqj = sq[j0 + mcol];
    f32x16 acc = {0.0f};
    acc = __builtin_amdgcn_mfma_f32_32x32x16_f16(afrag, bfrag, acc, 0, 0, 0);
    #pragma unroll
    for (int r = 0; r < 8; ++r) {
      const float d2a = fmaf(-2.0f, acc[r], sqi8[r] + sqj);
      if (d2a <= taug8[r]) {             // self passes; filtered in Phase C
        const int row = (r >> 2) * 8 + 4 * half + (r & 3);
        const int p = atomicAdd(&scnt[row], 1);
        if (p < CAP) sbuf[row][p] = (unsigned short)(j0 + mcol);
      }
    }
  }
  __syncthreads();

  // ===================== Phase C: exact fp32 re-score + top-16 ===============
  #pragma unroll
  for (int s = 0; s < 2; ++s) {
    const int lq = wave * 2 + s;         // query-in-block 0..15
    const int qg = qbase + lq;           // global query id
    const int cq = scnt[lq];
    const int nread = (cq < CAP) ? cq : CAP;

    float ci[16];
    {
      const float4* cp = (const float4*)(coords + qg * 16);
      *(float4*)&ci[0] = cp[0]; *(float4*)&ci[4] = cp[1];
      *(float4*)&ci[8] = cp[2]; *(float4*)&ci[12] = cp[3];
    }
    const float sqiq = sq[qg];

    u64 k6[6];
    #pragma unroll
    for (int t = 0; t < 6; ++t) k6[t] = ((u64)(0x7F000000u + t) << 32);
    u64 kmax6 = ((u64)0x7F000005u << 32);

    #pragma unroll
    for (int t = 0; t < CAP / 64; ++t) { // <=6 offers/lane: no eviction
      const int idx = t * 64 + lane;
      u64 key = ~0ull;
      if (idx < nread) {
        const int jj = sbuf[lq][idx];
        if (jj != qg) {
          const float4* cp = (const float4*)(coords + jj * 16);
          float cj[16];
          *(float4*)&cj[0]  = cp[0]; *(float4*)&cj[4]  = cp[1];
          *(float4*)&cj[8]  = cp[2]; *(float4*)&cj[12] = cp[3];
          float dot = 0.0f;
          #pragma unroll
          for (int d = 0; d < 16; ++d) dot = fmaf(ci[d], cj[d], dot);
          const float d2 = fmaxf(fmaf(-2.0f, dot, sqiq + sq[jj]), 0.0f);
          key = ((u64)__float_as_uint(d2) << 32) | (unsigned)jj;
        }
      }
      ins6(key, k6, kmax6);
    }

    u64 lmin = k6[0];
    #pragma unroll
    for (int t = 1; t < 6; ++t) lmin = (k6[t] < lmin) ? k6[t] : lmin;

    float aggv = 0.0f;
    for (int r = 0; r < KNN; ++r) {
      const u64 m = minbfly(lmin);
      if (lmin == m) {
        #pragma unroll
        for (int t = 0; t < 6; ++t) k6[t] = (k6[t] == m) ? ~0ull : k6[t];
        lmin = k6[0];
        #pragma unroll
        for (int t = 1; t < 6; ++t) lmin = (k6[t] < lmin) ? k6[t] : lmin;
      }
      const unsigned hi = (unsigned)(m >> 32);
      const bool ok = hi < 0x7F000000u;
      const float w = ok ? expf(-__uint_as_float(hi)) : 0.0f;
      const int jj = ok ? (int)(unsigned)(m & 0xFFFFFFFFull) : 0;
      aggv = fmaf(w, feats[jj * 64 + lane], aggv);
    }

    if (cq > CAP) {
      // overflow (P ~ 1e-4/run): slow-exact 16x ascending argmin full scan,
      // identical to the previously-separate fixup kernel's exact path.
      aggv = 0.0f;
      u64 prev = 0;
      for (int r = 0; r < KNN; ++r) {
        u64 best = ~0ull;
        for (int j = lane; j < N_PTS; j += 64) {
          float dot = 0.0f;
          #pragma unroll
          for (int d = 0; d < 16; ++d) dot = fmaf(ci[d], coords[j * 16 + d], dot);
          const float d2 = fmaxf(fmaf(-2.0f, dot, sqiq + sq[j]), 0.0f);
          const unsigned hi = (j == qg) ? 0xFFFFFFFFu : __float_as_uint(d2);
          const u64 key = ((u64)hi << 32) | (unsigned)j;
          const bool cand = (r == 0) || (key > prev);
          if (cand && key < best) best = key;
        }
        const u64 m = minbfly(best);
        prev = m;
        const unsigned hi = (unsigned)(m >> 32);
        const bool ok = hi < 0x7F000000u;
        const float w = ok ? expf(-__uint_as_float(hi)) : 0.0f;
        const int jj = ok ? (int)(unsigned)(m & 0xFFFFFFFFull) : 0;
        aggv = fmaf(w, feats[jj * 64 + lane], aggv);
      }
    }

    aggS[lq][lane] = aggv;
    featS[lq][lane] = feats[qg * 64 + lane];
  }

  // ===================== Epilogue: fused out GEMM (16 rows/block) ============
  __syncthreads();
  const int row = tid >> 5;        // 0..15
  const int c0 = tid & 31;         // cols c0 and c0+32
  float acc0 = bo[c0], acc1 = bo[c0 + 32];
  #pragma unroll
  for (int f = 0; f < 64; ++f) {
    const float fv = featS[row][f];
    const float av = aggS[row][f];
    acc0 = fmaf(fv, Wo[f * 64 + c0],        acc0);
    acc1 = fmaf(fv, Wo[f * 64 + c0 + 32],   acc1);
    acc0 = fmaf(av, Wo[(64 + f) * 64 + c0],      acc0);
    acc1 = fmaf(av, Wo[(64 + f) * 64 + c0 + 32], acc1);
  }
  const int orow = qbase + row;
  out[orow * 64 + c0]      = acc0;
  out[orow * 64 + c0 + 32] = acc1;
}

extern "C" void kernel_launch(void* const* d_in, const int* in_sizes, int n_in,
                              void* d_out, int out_size, void* d_ws, size_t ws_size,
                              hipStream_t stream) {
  const float* x  = (const float*)d_in[0];
  const float* Wf = (const float*)d_in[1];
  const float* bf = (const float*)d_in[2];
  const float* Wl = (const float*)d_in[3];
  const float* bl = (const float*)d_in[4];
  const float* Wo = (const float*)d_in[5];
  const float* bo = (const float*)d_in[6];
  float* out = (float*)d_out;

  char* ws = (char*)d_ws;
  float*     feats    = (float*)(ws);                 // 3,072,000 B
  float*     coords   = (float*)(ws + 3072000);       //   768,000 B
  float*     sqv      = (float*)(ws + 3840000);       //    48,000 B
  _Float16*  coords_h = (_Float16*)(ws + 3888000);    //   384,000 B

  encoder_kernel<<<3000, 256, 0, stream>>>(x, Wf, bf, Wl, bl, feats, coords, coords_h, sqv);
  knn_agg_kernel<<<N_PTS / QB, 512, 0, stream>>>(coords, coords_h, sqv, feats, Wo, bo, out);
}